// Round 3
// baseline (107.601 us; speedup 1.0000x reference)
//
#include <hip/hip_runtime.h>
#include <math.h>

typedef _Float16 half8   __attribute__((ext_vector_type(8)));
typedef _Float16 half4v  __attribute__((ext_vector_type(4)));
typedef float    float4v __attribute__((ext_vector_type(4)));

#define BM    64
#define KDIM  256
#define WSTR  264   // halves per wh row (256 + 8 pad) -> 528 B row stride, 16B-aligned
#define HSW   65    // fp32 h-tile stride: (r+k)%32 -> 2-way (free)

__global__ __launch_bounds__(256, 4)
void qc_fused(const float* __restrict__ x,
              const float* __restrict__ W1,
              const float* __restrict__ b1,
              const float* __restrict__ W2,
              const float* __restrict__ b2,
              const float* __restrict__ qw,
              float* __restrict__ out)
{
    // wh (fp16 W1, staged) reused as hs (fp32 h tile) after the MFMA loop
    __shared__ __align__(16) unsigned char smem_raw[BM * WSTR * 2];  // 33792 B
    __shared__ float w2s[256];
    __shared__ float b1s[64];
    __shared__ float b2s[4];
    __shared__ float trig[32];        // [layer][qubit][{cy,sy,cz,sz}]
    __shared__ float angs[BM * 4];

    _Float16* wh = (_Float16*)smem_raw;
    float*    hs = (float*)smem_raw;

    const int tid  = threadIdx.x;
    const int lane = tid & 63;
    const int wv   = tid >> 6;        // wave -> rows wv*16 .. wv*16+15
    const int m    = lane & 15;
    const int q    = lane >> 4;
    const int row0 = blockIdx.x * BM;

    // ---- x: direct global -> register A-fragments (each element read once) ----
    // A-frag layout: A[m][k = q*8 + j]; frag f covers k = f*32 + q*8 .. +7
    const float* xrow = x + (size_t)(row0 + wv * 16 + m) * KDIM + q * 8;
    float4v xv[16];
    #pragma unroll
    for (int f = 0; f < 8; ++f) {
        xv[2 * f]     = *(const float4v*)(xrow + f * 32);
        xv[2 * f + 1] = *(const float4v*)(xrow + f * 32 + 4);
    }

    // ---- small per-block setup (before first sync) ----
    w2s[tid] = W2[tid];               // 4*64 = 256
    if (tid < 64) b1s[tid] = b1[tid];
    if (tid < 4)  b2s[tid] = b2[tid];
    if (tid < 8) {
        int l = tid >> 2, i = tid & 3;
        float wy = qw[(l * 4 + i) * 2 + 0];
        float wz = qw[(l * 4 + i) * 2 + 1];
        float sy, cy, sz, cz;
        sincosf(0.5f * wy, &sy, &cy);
        sincosf(0.5f * wz, &sz, &cz);
        trig[(l * 4 + i) * 4 + 0] = cy;
        trig[(l * 4 + i) * 4 + 1] = sy;
        trig[(l * 4 + i) * 4 + 2] = cz;
        trig[(l * 4 + i) * 4 + 3] = sz;
    }

    // ---- stage W1 (64x256) fp32 -> fp16 into LDS ----
    {
        const int rw = tid >> 2;            // 0..63
        const int c0 = (tid & 3) * 4;       // 0,4,8,12
        const float* wrow = W1 + (size_t)rw * KDIM;
        #pragma unroll
        for (int j = 0; j < 16; ++j) {
            float4v v = *(const float4v*)(wrow + c0 + 16 * j);
            half4v h;
            h[0] = (_Float16)v[0]; h[1] = (_Float16)v[1];
            h[2] = (_Float16)v[2]; h[3] = (_Float16)v[3];
            *(half4v*)&wh[rw * WSTR + c0 + 16 * j] = h;   // 2-way banks: free
        }
    }

    // ---- cvt x fragments fp32 -> fp16 ----
    half8 afr[8];
    #pragma unroll
    for (int f = 0; f < 8; ++f) {
        afr[f][0] = (_Float16)xv[2 * f][0];
        afr[f][1] = (_Float16)xv[2 * f][1];
        afr[f][2] = (_Float16)xv[2 * f][2];
        afr[f][3] = (_Float16)xv[2 * f][3];
        afr[f][4] = (_Float16)xv[2 * f + 1][0];
        afr[f][5] = (_Float16)xv[2 * f + 1][1];
        afr[f][6] = (_Float16)xv[2 * f + 1][2];
        afr[f][7] = (_Float16)xv[2 * f + 1][3];
    }

    __syncthreads();

    // ---- MFMA: K=256 in 8 steps of 32, wave tile 16 rows x 64 cols ----
    float4v acc[4] = {};
    #pragma unroll
    for (int f = 0; f < 8; ++f) {
        const int ko = f * 32 + q * 8;
        #pragma unroll
        for (int b = 0; b < 4; ++b) {
            half8 bf = *(const half8*)&wh[(16 * b + m) * WSTR + ko];
            acc[b] = __builtin_amdgcn_mfma_f32_16x16x32_f16(afr[f], bf, acc[b], 0, 0, 0);
        }
    }
    __syncthreads();   // all waves done reading wh before hs overwrites it

    // ---- bias + relu -> hs (C/D: row = q*4+reg, col = m) ----
    #pragma unroll
    for (int b = 0; b < 4; ++b) {
        #pragma unroll
        for (int i = 0; i < 4; ++i) {
            int row = wv * 16 + q * 4 + i;
            int col = 16 * b + m;
            hs[row * HSW + col] = fmaxf(acc[b][i] + b1s[col], 0.0f);
        }
    }
    __syncthreads();

    // ---- GEMM2 + tanh: 256 threads = 64 rows x 4 outputs ----
    {
        int r = tid & 63, qi = tid >> 6;      // qi wave-uniform -> w2s reads scalar
        float s = b2s[qi];
        #pragma unroll 8
        for (int k = 0; k < 64; ++k)
            s = fmaf(hs[r * HSW + k], w2s[qi * 64 + k], s);
        angs[r * 4 + qi] = tanhf(s);
    }
    __syncthreads();

    // ---- quantum circuit: one thread per row ----
    if (tid < 64) {
        float ca[4], sa[4];
        #pragma unroll
        for (int i = 0; i < 4; ++i)
            __sincosf(0.5f * angs[tid * 4 + i], &sa[i], &ca[i]);

        // state idx = w0*8 + w1*4 + w2*2 + w3
        float re[16], im[16];
        #pragma unroll
        for (int idx = 0; idx < 16; ++idx) {
            re[idx] = (idx & 8 ? sa[0] : ca[0]) * (idx & 4 ? sa[1] : ca[1]) *
                      (idx & 2 ? sa[2] : ca[2]) * (idx & 1 ? sa[3] : ca[3]);
            im[idx] = 0.0f;
        }
        #pragma unroll
        for (int l = 0; l < 2; ++l) {
            #pragma unroll
            for (int i = 0; i < 4; ++i) {
                const float cy = trig[(l * 4 + i) * 4 + 0];
                const float sy = trig[(l * 4 + i) * 4 + 1];
                const float cz = trig[(l * 4 + i) * 4 + 2];
                const float sz = trig[(l * 4 + i) * 4 + 3];
                const int mq = 8 >> i;
                #pragma unroll
                for (int idx = 0; idx < 16; ++idx) {
                    if (!(idx & mq)) {
                        int j = idx | mq;
                        float ar = re[idx], ai = im[idx], br = re[j], bi = im[j];
                        re[idx] = fmaf(cy, ar, -sy * br);
                        im[idx] = fmaf(cy, ai, -sy * bi);
                        re[j]   = fmaf(sy, ar,  cy * br);
                        im[j]   = fmaf(sy, ai,  cy * bi);
                    }
                }
                #pragma unroll
                for (int idx = 0; idx < 16; ++idx) {
                    float sgn = (idx & mq) ? sz : -sz;
                    float ar = re[idx], ai = im[idx];
                    re[idx] = fmaf(ar, cz, -ai * sgn);
                    im[idx] = fmaf(ar, sgn, ai * cz);
                }
            }
            #pragma unroll
            for (int c = 0; c < 4; ++c) {
                int t  = (c + 1) & 3;
                int mc = 8 >> c, mt = 8 >> t;
                #pragma unroll
                for (int idx = 0; idx < 16; ++idx) {
                    if ((idx & mc) && !(idx & mt)) {
                        int j = idx | mt;
                        float tr = re[idx]; re[idx] = re[j]; re[j] = tr;
                        float ti = im[idx]; im[idx] = im[j]; im[j] = ti;
                    }
                }
            }
        }
        float z = 0.0f;
        #pragma unroll
        for (int idx = 0; idx < 16; ++idx) {
            float p = re[idx] * re[idx] + im[idx] * im[idx];
            z += (idx & 8) ? -p : p;
        }
        out[row0 + tid] = z;
    }
}

extern "C" void kernel_launch(void* const* d_in, const int* in_sizes, int n_in,
                              void* d_out, int out_size, void* d_ws, size_t ws_size,
                              hipStream_t stream) {
    const float* x  = (const float*)d_in[0];
    const float* W1 = (const float*)d_in[1];
    const float* b1 = (const float*)d_in[2];
    const float* W2 = (const float*)d_in[3];
    const float* b2 = (const float*)d_in[4];
    const float* qw = (const float*)d_in[5];
    float* out = (float*)d_out;
    const int B = in_sizes[0] / KDIM;   // 65536
    qc_fused<<<B / BM, 256, 0, stream>>>(x, W1, b1, W2, b2, qw, out);
}